// Round 1
// baseline (379.140 us; speedup 1.0000x reference)
//
#include <hip/hip_runtime.h>
#include <hip/hip_bf16.h>
#include <math.h>

// Problem constants: B=16, D=128, OUT=128, M=100000 (runtime from in_sizes).
// Pipeline:
//   K1: A[b][o]   = sum_d xx[b,d] * W1[o, d]                      (anchor part)
//   K2: np[m][o]  = sum_d in[m,d] * W1[o, 128+d]   (fp32 reg-tiled GEMM, 64-row tiles)
//       S[b][m]   = sum_o relu(A[b][o] + np[m][o]) * W2[o]        (+ per-block max)
//   K3: gmax[b]   = max over blocks
//   K4: partial l[b], acc[b][d] = sum_m exp(S-gmax) * in[m][d]    (256-row tiles)
//   K5: out[b][d] = sum acc / sum l

__global__ void k1_anchor(const float* __restrict__ xx, const float* __restrict__ W1,
                          float* __restrict__ A) {
    int idx = blockIdx.x * 256 + threadIdx.x;   // 8 blocks * 256 = 2048 = 16*128
    int b = idx >> 7, o = idx & 127;
    float acc = 0.f;
#pragma unroll 4
    for (int d = 0; d < 128; ++d) acc += xx[b * 128 + d] * W1[o * 256 + d];
    A[idx] = acc;
}

__global__ __launch_bounds__(256) void k2_scores(
    const float* __restrict__ in, const float* __restrict__ W1,
    const float* __restrict__ W2, const float* __restrict__ A,
    float* __restrict__ S, float* __restrict__ pmax, int M) {
    __shared__ float ins[64 * 132];   // input tile [64 m][128 d], pad 132 (16B-aligned rows)
    __shared__ float w1s[128 * 36];   // W1 chunk  [128 o][32 d], pad 36
    __shared__ float sl[16 * 68];     // scores    [16 b][64 m]

    const int tid = threadIdx.x;
    const int bid = blockIdx.x;
    const int m0 = bid * 64;

    // ---- load input tile (coalesced float4), zero-pad tail rows ----
#pragma unroll
    for (int i = 0; i < 8; ++i) {
        int idx = tid + 256 * i;             // 2048 float4s
        int r = idx >> 5, c4 = (idx & 31) << 2;
        float4 v = make_float4(0.f, 0.f, 0.f, 0.f);
        if (m0 + r < M) v = *(const float4*)&in[(size_t)(m0 + r) * 128 + c4];
        *(float4*)&ins[r * 132 + c4] = v;
    }

    const int tx = tid & 15;   // o-group: o = tx + 16*oi
    const int ty = tid >> 4;   // m-group: m = ty*4 + mi
    float acc[4][8];
#pragma unroll
    for (int mi = 0; mi < 4; ++mi)
#pragma unroll
        for (int oi = 0; oi < 8; ++oi) acc[mi][oi] = 0.f;

    // ---- np GEMM: 4 d-chunks of 32 ----
    for (int dc = 0; dc < 4; ++dc) {
        __syncthreads();
#pragma unroll
        for (int i = 0; i < 4; ++i) {
            int idx = tid + 256 * i;          // 1024 float4s: [o][c]
            int o = idx >> 3, c4 = (idx & 7) << 2;
            *(float4*)&w1s[o * 36 + c4] =
                *(const float4*)&W1[o * 256 + 128 + dc * 32 + c4];
        }
        __syncthreads();
#pragma unroll
        for (int c4i = 0; c4i < 8; ++c4i) {
            int c = c4i * 4;
            float4 am[4], bo[8];
#pragma unroll
            for (int mi = 0; mi < 4; ++mi)
                am[mi] = *(float4*)&ins[(ty * 4 + mi) * 132 + dc * 32 + c];
#pragma unroll
            for (int oi = 0; oi < 8; ++oi)
                bo[oi] = *(float4*)&w1s[(tx + 16 * oi) * 36 + c];
#pragma unroll
            for (int mi = 0; mi < 4; ++mi)
#pragma unroll
                for (int oi = 0; oi < 8; ++oi)
                    acc[mi][oi] += am[mi].x * bo[oi].x + am[mi].y * bo[oi].y +
                                   am[mi].z * bo[oi].z + am[mi].w * bo[oi].w;
        }
    }

    // ---- scores: s[b][m] = sum_o relu(A[b][o] + np[m][o]) * w2[o] ----
    float w2v[8];
#pragma unroll
    for (int oi = 0; oi < 8; ++oi) w2v[oi] = W2[tx + 16 * oi];

#pragma unroll
    for (int b = 0; b < 16; ++b) {
        float av[8];
#pragma unroll
        for (int oi = 0; oi < 8; ++oi) av[oi] = A[b * 128 + tx + 16 * oi];
        float sp[4];
#pragma unroll
        for (int mi = 0; mi < 4; ++mi) {
            float sacc = 0.f;
#pragma unroll
            for (int oi = 0; oi < 8; ++oi)
                sacc += fmaxf(acc[mi][oi] + av[oi], 0.f) * w2v[oi];
            sp[mi] = sacc;
        }
        // reduce over the 16 tx-lanes (xor masks 1,2,4,8 stay inside each 16-group)
#pragma unroll
        for (int off = 1; off < 16; off <<= 1) {
#pragma unroll
            for (int mi = 0; mi < 4; ++mi) sp[mi] += __shfl_xor(sp[mi], off, 64);
        }
        if (tx == b) {
#pragma unroll
            for (int mi = 0; mi < 4; ++mi) sl[b * 68 + ty * 4 + mi] = sp[mi];
        }
    }
    __syncthreads();

    // ---- write scores (coalesced) + per-block per-b max ----
#pragma unroll
    for (int i = 0; i < 4; ++i) {
        int idx = tid + 256 * i;   // 1024 = 16b * 64m
        int b = idx >> 6, ml = idx & 63;
        if (m0 + ml < M) S[(size_t)b * M + m0 + ml] = sl[b * 68 + ml];
    }
    if (tid < 16) {
        float mx = -INFINITY;
        int lim = M - m0; if (lim > 64) lim = 64;
        for (int ml = 0; ml < lim; ++ml) mx = fmaxf(mx, sl[tid * 68 + ml]);
        pmax[bid * 16 + tid] = mx;
    }
}

__global__ void k3_gmax(const float* __restrict__ pmax, float* __restrict__ gmax,
                        int nb2) {
    __shared__ float red[16 * 17];
    int t = threadIdx.x;
    int b = t & 15, g = t >> 4;
    float mx = -INFINITY;
    for (int i = g; i < nb2; i += 16) mx = fmaxf(mx, pmax[i * 16 + b]);
    red[b * 17 + g] = mx;
    __syncthreads();
    if (t < 16) {
        float m2 = -INFINITY;
        for (int g2 = 0; g2 < 16; ++g2) m2 = fmaxf(m2, red[t * 17 + g2]);
        gmax[t] = m2;
    }
}

__global__ __launch_bounds__(256) void k4_pool(
    const float* __restrict__ in, const float* __restrict__ S,
    const float* __restrict__ gmax, float* __restrict__ pl,
    float* __restrict__ pacc, int M) {
    __shared__ float intr[128 * 65];   // input sub-tile transposed [d][m]
    __shared__ float ps[64 * 20];      // p [m][b], 16B-aligned rows
    __shared__ float gm[16];
    const int tid = threadIdx.x, bid = blockIdx.x;
    const int m0 = bid * 256;
    if (tid < 16) gm[tid] = gmax[tid];

    const int dd = tid & 127, bg = tid >> 7;   // thread owns (d=dd, b=bg*8+j)
    float acc[8], lacc[8];
#pragma unroll
    for (int j = 0; j < 8; ++j) { acc[j] = 0.f; lacc[j] = 0.f; }

    for (int sc = 0; sc < 4; ++sc) {
        __syncthreads();
        // load 64-row input sub-tile, transposed into LDS
#pragma unroll
        for (int i = 0; i < 8; ++i) {
            int idx = tid + 256 * i;
            int r = idx >> 5, c4 = (idx & 31) << 2;
            int m = m0 + sc * 64 + r;
            float4 v = make_float4(0.f, 0.f, 0.f, 0.f);
            if (m < M) v = *(const float4*)&in[(size_t)m * 128 + c4];
            intr[(c4 + 0) * 65 + r] = v.x;
            intr[(c4 + 1) * 65 + r] = v.y;
            intr[(c4 + 2) * 65 + r] = v.z;
            intr[(c4 + 3) * 65 + r] = v.w;
        }
        // p = exp(S - gmax)
#pragma unroll
        for (int i = 0; i < 4; ++i) {
            int idx = tid + 256 * i;   // 1024 = 16b * 64m
            int ml = idx & 63, b = idx >> 6;
            int m = m0 + sc * 64 + ml;
            float v = 0.f;
            if (m < M) v = __expf(S[(size_t)b * M + m] - gm[b]);
            ps[ml * 20 + b] = v;
        }
        __syncthreads();
#pragma unroll 4
        for (int ml = 0; ml < 64; ++ml) {
            float4 p0 = *(float4*)&ps[ml * 20 + bg * 8];       // wave-broadcast
            float4 p1 = *(float4*)&ps[ml * 20 + bg * 8 + 4];
            float iv = intr[dd * 65 + ml];                     // conflict-free
            acc[0] += p0.x * iv; acc[1] += p0.y * iv;
            acc[2] += p0.z * iv; acc[3] += p0.w * iv;
            acc[4] += p1.x * iv; acc[5] += p1.y * iv;
            acc[6] += p1.z * iv; acc[7] += p1.w * iv;
            lacc[0] += p0.x; lacc[1] += p0.y; lacc[2] += p0.z; lacc[3] += p0.w;
            lacc[4] += p1.x; lacc[5] += p1.y; lacc[6] += p1.z; lacc[7] += p1.w;
        }
    }
#pragma unroll
    for (int j = 0; j < 8; ++j)
        pacc[((size_t)bid * 16 + bg * 8 + j) * 128 + dd] = acc[j];
    if ((tid & 127) == 0) {   // lane 0 of each bg half (lacc is wave-uniform)
#pragma unroll
        for (int j = 0; j < 8; ++j) pl[bid * 16 + bg * 8 + j] = lacc[j];
    }
}

__global__ void k5_out(const float* __restrict__ pl, const float* __restrict__ pacc,
                       float* __restrict__ out, int nb4) {
    __shared__ float reda[2 * 128];
    __shared__ float redl[2];
    int b = blockIdx.x, t = threadIdx.x;
    int dd = t & 127, half = t >> 7;
    float ls = 0.f, ac = 0.f;
    for (int blk = half; blk < nb4; blk += 2) {
        ls += pl[blk * 16 + b];
        ac += pacc[((size_t)blk * 16 + b) * 128 + dd];
    }
    reda[half * 128 + dd] = ac;
    if (dd == 0) redl[half] = ls;
    __syncthreads();
    if (half == 0)
        out[b * 128 + dd] = (reda[dd] + reda[128 + dd]) / (redl[0] + redl[1]);
}

extern "C" void kernel_launch(void* const* d_in, const int* in_sizes, int n_in,
                              void* d_out, int out_size, void* d_ws, size_t ws_size,
                              hipStream_t stream) {
    const float* xx = (const float*)d_in[0];
    const float* in = (const float*)d_in[1];
    // d_in[2] = adj, unused in forward math
    const float* W1 = (const float*)d_in[3];
    const float* W2 = (const float*)d_in[4];
    float* out = (float*)d_out;

    const int M = in_sizes[1] / 128;
    const int nb2 = (M + 63) / 64;
    const int nb4 = (M + 255) / 256;

    float* ws = (float*)d_ws;
    float* A    = ws;                         // 2048
    float* S    = A + 2048;                   // 16*M
    float* pmax = S + (size_t)16 * M;         // nb2*16
    float* gmax = pmax + (size_t)nb2 * 16;    // 16
    float* pl   = gmax + 16;                  // nb4*16
    float* pacc = pl + (size_t)nb4 * 16;      // nb4*16*128
    // total ~9.7 MB of d_ws

    k1_anchor<<<8, 256, 0, stream>>>(xx, W1, A);
    k2_scores<<<nb2, 256, 0, stream>>>(in, W1, W2, A, S, pmax, M);
    k3_gmax<<<1, 256, 0, stream>>>(pmax, gmax, nb2);
    k4_pool<<<nb4, 256, 0, stream>>>(in, S, gmax, pl, pacc, M);
    k5_out<<<16, 256, 0, stream>>>(pl, pacc, out, nb4);
}

// Round 2
// 246.395 us; speedup vs baseline: 1.5387x; 1.5387x over previous
//
#include <hip/hip_runtime.h>
#include <hip/hip_bf16.h>
#include <math.h>

// B=16, D=128, OUT=128, M=100000 (runtime).
// Pipeline:
//   K0: w1b[o][d] = bf16(W1[o][128+d])                 (one-time W1 node-half convert)
//   K1: A[b][o]   = sum_d xx[b,d] * W1[o, d]           (anchor part, fp32)
//   K2: np[m][o]  via bf16 MFMA 16x16x32 (no LDS GEMM staging; A-frags from global
//       + in-reg cvt, B-frags from pre-converted w1b in L2)
//       S[b][m]   = sum_o relu(A[b][o] + np[m][o]) * W2[o]   (+ per-block max)
//   K3: gmax[b]   (16 blocks)
//   K4: partial l[b], acc[b][d] = sum_m exp(S-gmax) * in[m][d]
//   K5: out[b][d] = sum acc / sum l

typedef __attribute__((ext_vector_type(8))) short bf16x8;
typedef __attribute__((ext_vector_type(4))) float f32x4;

__device__ __forceinline__ short f2bs(float f) {
    __hip_bfloat16 h = __float2bfloat16(f);
    return *reinterpret_cast<short*>(&h);
}

__global__ void k0_w1bf(const float* __restrict__ W1, ushort* __restrict__ w1b) {
    int idx = blockIdx.x * 256 + threadIdx.x;   // 64 blocks * 256 = 16384 = 128o * 128d
    int o = idx >> 7, d = idx & 127;
    w1b[idx] = (ushort)f2bs(W1[o * 256 + 128 + d]);
}

__global__ void k1_anchor(const float* __restrict__ xx, const float* __restrict__ W1,
                          float* __restrict__ A) {
    int idx = blockIdx.x * 256 + threadIdx.x;   // 8 blocks * 256 = 2048 = 16*128
    int b = idx >> 7, o = idx & 127;
    float acc = 0.f;
#pragma unroll 4
    for (int d = 0; d < 128; ++d) acc += xx[b * 128 + d] * W1[o * 256 + d];
    A[idx] = acc;
}

__global__ __launch_bounds__(256) void k2_scores(
    const float* __restrict__ in, const ushort* __restrict__ w1b,
    const float* __restrict__ W2, const float* __restrict__ A,
    float* __restrict__ S, float* __restrict__ pmax, int M) {
    __shared__ float As[16 * 132];   // A[b][o], pad 132
    __shared__ float w2s[128];
    __shared__ float sl[16 * 68];    // scores [16 b][64 m]

    const int tid = threadIdx.x;
    const int bid = blockIdx.x;
    const int m0 = bid * 64;
    const int wave = tid >> 6, lane = tid & 63;
    const int c = lane & 15;         // MFMA col / A-row lane index
    const int q = lane >> 4;         // quad: k-offset q*8, D-rows q*4..q*4+3

    if (tid < 128) w2s[tid] = W2[tid];
#pragma unroll
    for (int i = 0; i < 8; ++i) {
        int idx = tid + 256 * i;     // 2048 = 16b * 128o
        As[(idx >> 7) * 132 + (idx & 127)] = A[idx];
    }
    __syncthreads();

    // ---- np GEMM via MFMA: wave owns m-rows [m0+wave*16, +16), full 128 o ----
    const int row = m0 + wave * 16 + c;
    const bool valid = row < M;
    const float* arow = in + (size_t)row * 128;

    f32x4 acc[8];
#pragma unroll
    for (int ot = 0; ot < 8; ++ot) acc[ot] = (f32x4){0.f, 0.f, 0.f, 0.f};

#pragma unroll
    for (int kb = 0; kb < 4; ++kb) {
        const int off = kb * 32 + q * 8;
        float4 f0 = make_float4(0.f, 0.f, 0.f, 0.f), f1 = f0;
        if (valid) {
            f0 = *(const float4*)(arow + off);
            f1 = *(const float4*)(arow + off + 4);
        }
        bf16x8 av;
        av[0] = f2bs(f0.x); av[1] = f2bs(f0.y); av[2] = f2bs(f0.z); av[3] = f2bs(f0.w);
        av[4] = f2bs(f1.x); av[5] = f2bs(f1.y); av[6] = f2bs(f1.z); av[7] = f2bs(f1.w);
#pragma unroll
        for (int ot = 0; ot < 8; ++ot) {
            bf16x8 bv = *(const bf16x8*)(w1b + (ot * 16 + c) * 128 + off);
            acc[ot] = __builtin_amdgcn_mfma_f32_16x16x32_bf16(av, bv, acc[ot], 0, 0, 0);
        }
    }
    // lane now holds np[m0+wave*16 + q*4+r][ot*16+c] in acc[ot][r]

    // ---- scores: s[b][m] = sum_o relu(np + A[b][o]) * w2[o] ----
    float w2v[8];
#pragma unroll
    for (int ot = 0; ot < 8; ++ot) w2v[ot] = w2s[ot * 16 + c];

#pragma unroll
    for (int b = 0; b < 16; ++b) {
        float sp[4] = {0.f, 0.f, 0.f, 0.f};
#pragma unroll
        for (int ot = 0; ot < 8; ++ot) {
            float av = As[b * 132 + ot * 16 + c];
            float w = w2v[ot];
#pragma unroll
            for (int r = 0; r < 4; ++r)
                sp[r] += fmaxf(acc[ot][r] + av, 0.f) * w;
        }
#pragma unroll
        for (int off2 = 1; off2 < 16; off2 <<= 1)
#pragma unroll
            for (int r = 0; r < 4; ++r) sp[r] += __shfl_xor(sp[r], off2, 64);
        if (c == b) {
#pragma unroll
            for (int r = 0; r < 4; ++r)
                sl[b * 68 + wave * 16 + q * 4 + r] = sp[r];
        }
    }
    __syncthreads();

    // ---- write scores (coalesced) + per-block per-b max ----
#pragma unroll
    for (int i = 0; i < 4; ++i) {
        int idx = tid + 256 * i;   // 1024 = 16b * 64m
        int b = idx >> 6, ml = idx & 63;
        if (m0 + ml < M) S[(size_t)b * M + m0 + ml] = sl[b * 68 + ml];
    }
    if (tid < 16) {
        float mx = -INFINITY;
        int lim = M - m0; if (lim > 64) lim = 64;
        for (int ml = 0; ml < lim; ++ml) mx = fmaxf(mx, sl[tid * 68 + ml]);
        pmax[bid * 16 + tid] = mx;
    }
}

__global__ void k3_gmax(const float* __restrict__ pmax, float* __restrict__ gmax,
                        int nb2) {
    __shared__ float red[4];
    int b = blockIdx.x, t = threadIdx.x;
    float mx = -INFINITY;
    for (int i = t; i < nb2; i += 256) mx = fmaxf(mx, pmax[i * 16 + b]);
#pragma unroll
    for (int off = 1; off < 64; off <<= 1) mx = fmaxf(mx, __shfl_xor(mx, off, 64));
    if ((t & 63) == 0) red[t >> 6] = mx;
    __syncthreads();
    if (t == 0) gmax[b] = fmaxf(fmaxf(red[0], red[1]), fmaxf(red[2], red[3]));
}

__global__ __launch_bounds__(256) void k4_pool(
    const float* __restrict__ in, const float* __restrict__ S,
    const float* __restrict__ gmax, float* __restrict__ pl,
    float* __restrict__ pacc, int M) {
    __shared__ float ps[64 * 20];   // p [m][b], padded rows
    __shared__ float gm[16];
    const int tid = threadIdx.x, bid = blockIdx.x;
    const int m0 = bid * 256;
    if (tid < 16) gm[tid] = gmax[tid];
    const int dd = tid & 127, bg = tid >> 7;
    float acc[8];
    float lacc[4] = {0.f, 0.f, 0.f, 0.f};
#pragma unroll
    for (int j = 0; j < 8; ++j) acc[j] = 0.f;
    __syncthreads();

    for (int sc = 0; sc < 4; ++sc) {
        // p = exp(S - gmax); fold l-sum here (each (b,ml) slot computed once)
#pragma unroll
        for (int i = 0; i < 4; ++i) {
            int idx = tid + 256 * i;   // 1024 = 16b * 64m; b = (tid>>6) + 4*i
            int ml = idx & 63, b = idx >> 6;
            int m = m0 + sc * 64 + ml;
            float v = 0.f;
            if (m < M) v = __expf(S[(size_t)b * M + m] - gm[b]);
            ps[ml * 20 + b] = v;
            lacc[i] += v;
        }
        __syncthreads();
#pragma unroll 4
        for (int ml = 0; ml < 64; ++ml) {
            int m = m0 + sc * 64 + ml;
            float iv = 0.f;
            if (m < M) iv = in[(size_t)m * 128 + dd];   // coalesced per wave
            float4 p0 = *(float4*)&ps[ml * 20 + bg * 8];
            float4 p1 = *(float4*)&ps[ml * 20 + bg * 8 + 4];
            acc[0] += p0.x * iv; acc[1] += p0.y * iv;
            acc[2] += p0.z * iv; acc[3] += p0.w * iv;
            acc[4] += p1.x * iv; acc[5] += p1.y * iv;
            acc[6] += p1.z * iv; acc[7] += p1.w * iv;
        }
        __syncthreads();
    }
#pragma unroll
    for (int j = 0; j < 8; ++j)
        pacc[((size_t)bid * 16 + bg * 8 + j) * 128 + dd] = acc[j];
    // lacc[i] is the partial for b = (tid>>6)+4i, distinct ml per lane within a wave
#pragma unroll
    for (int i = 0; i < 4; ++i)
#pragma unroll
        for (int off = 1; off < 64; off <<= 1)
            lacc[i] += __shfl_xor(lacc[i], off, 64);
    if ((tid & 63) == 0) {
        int g = tid >> 6;
#pragma unroll
        for (int i = 0; i < 4; ++i) pl[bid * 16 + g + 4 * i] = lacc[i];
    }
}

__global__ void k5_out(const float* __restrict__ pl, const float* __restrict__ pacc,
                       float* __restrict__ out, int nb4) {
    __shared__ float reda[2 * 128];
    __shared__ float redl[2];
    int b = blockIdx.x, t = threadIdx.x;
    int dd = t & 127, half = t >> 7;
    float ls = 0.f, ac = 0.f;
    for (int blk = half; blk < nb4; blk += 2) {
        ls += pl[blk * 16 + b];
        ac += pacc[((size_t)blk * 16 + b) * 128 + dd];
    }
    reda[half * 128 + dd] = ac;
    if (dd == 0) redl[half] = ls;
    __syncthreads();
    if (half == 0)
        out[b * 128 + dd] = (reda[dd] + reda[128 + dd]) / (redl[0] + redl[1]);
}

extern "C" void kernel_launch(void* const* d_in, const int* in_sizes, int n_in,
                              void* d_out, int out_size, void* d_ws, size_t ws_size,
                              hipStream_t stream) {
    const float* xx = (const float*)d_in[0];
    const float* in = (const float*)d_in[1];
    // d_in[2] = adj, unused in forward math
    const float* W1 = (const float*)d_in[3];
    const float* W2 = (const float*)d_in[4];
    float* out = (float*)d_out;

    const int M = in_sizes[1] / 128;
    const int nb2 = (M + 63) / 64;
    const int nb4 = (M + 255) / 256;

    float* ws = (float*)d_ws;
    float* A    = ws;                         // 2048
    float* S    = A + 2048;                   // 16*M
    float* pmax = S + (size_t)16 * M;         // nb2*16
    float* gmax = pmax + (size_t)nb2 * 16;    // 16
    float* pl   = gmax + 16;                  // nb4*16
    float* pacc = pl + (size_t)nb4 * 16;      // nb4*16*128
    ushort* w1b = (ushort*)(pacc + (size_t)nb4 * 16 * 128);  // 16384 ushorts (32 KB)
    // total ~9.8 MB of d_ws

    k0_w1bf<<<64, 256, 0, stream>>>(W1, w1b);
    k1_anchor<<<8, 256, 0, stream>>>(xx, W1, A);
    k2_scores<<<nb2, 256, 0, stream>>>(in, w1b, W2, A, S, pmax, M);
    k3_gmax<<<16, 256, 0, stream>>>(pmax, gmax, nb2);
    k4_pool<<<nb4, 256, 0, stream>>>(in, S, gmax, pl, pacc, M);
    k5_out<<<16, 256, 0, stream>>>(pl, pacc, out, nb4);
}

// Round 3
// 175.355 us; speedup vs baseline: 2.1621x; 1.4051x over previous
//
#include <hip/hip_runtime.h>
#include <hip/hip_bf16.h>
#include <math.h>

// B=16, D=128, OUT=128, M runtime (100000).
// kA : blocks 0-63: w1b = bf16(W1 node half); blocks 64-71: A[b][o] anchor GEMM (LDS-staged)
// kB : fused per-64-row-block: np via bf16 MFMA -> scores -> local softmax -> pooled
//      partials (lmax, lsum fp32; pacc bf16)
// kC1: 16 b x 16 splits: global-max rescale + partial reduction over blocks
// kC2: final 16-way reduce -> out

typedef __attribute__((ext_vector_type(8))) short bf16x8;
typedef __attribute__((ext_vector_type(4))) float f32x4;

__device__ __forceinline__ short f2bs(float f) {
    __hip_bfloat16 h = __float2bfloat16(f);
    return *reinterpret_cast<short*>(&h);
}
__device__ __forceinline__ float bs2f(ushort u) {
    union { unsigned int i; float f; } v; v.i = ((unsigned)u) << 16; return v.f;
}

__global__ __launch_bounds__(256) void kA(const float* __restrict__ W1,
                                          const float* __restrict__ xx,
                                          ushort* __restrict__ w1b,
                                          float* __restrict__ A) {
    const int bi = blockIdx.x, t = threadIdx.x;
    if (bi < 64) {
        int idx = bi * 256 + t;              // 16384 = 128o * 128d
        int o = idx >> 7, d = idx & 127;
        w1b[idx] = (ushort)f2bs(W1[o * 256 + 128 + d]);
        return;
    }
    // anchor part: A[b][o] = sum_d xx[b,d] * W1[o,d], 16 o's per block
    __shared__ float xxs[16 * 132];
    __shared__ float w1s[16 * 132];
    const int og0 = (bi - 64) * 16;
#pragma unroll
    for (int i = 0; i < 2; ++i) {
        int idx = t + 256 * i;               // 512 float4 = 16 rows * 32
        int r = idx >> 5, c4 = (idx & 31) << 2;
        *(float4*)&xxs[r * 132 + c4] = *(const float4*)&xx[r * 128 + c4];
        *(float4*)&w1s[r * 132 + c4] = *(const float4*)&W1[(og0 + r) * 256 + c4];
    }
    __syncthreads();
    const int ol = t >> 4, b = t & 15;
    float acc = 0.f;
#pragma unroll
    for (int d4 = 0; d4 < 32; ++d4) {
        float4 xv = *(float4*)&xxs[b * 132 + d4 * 4];
        float4 wv = *(float4*)&w1s[ol * 132 + d4 * 4];
        acc += xv.x * wv.x + xv.y * wv.y + xv.z * wv.z + xv.w * wv.w;
    }
    A[b * 128 + og0 + ol] = acc;
}

__global__ __launch_bounds__(256, 6) void kB(
    const float* __restrict__ in, const ushort* __restrict__ w1b,
    const float* __restrict__ W2, const float* __restrict__ A,
    float* __restrict__ lmax_g, float* __restrict__ lsum_g,
    ushort* __restrict__ pacc, int M) {
    __shared__ float As[16 * 132];   // A[b][o]
    __shared__ float w2s[128];
    __shared__ float sl[16 * 68];    // scores [b][ml]
    __shared__ float ps[64 * 20];    // p      [ml][b]

    const int tid = threadIdx.x, bid = blockIdx.x;
    const int m0 = bid * 64;
    const int w = tid >> 6, lane = tid & 63;
    const int c = lane & 15, q = lane >> 4;

    if (tid < 128) w2s[tid] = W2[tid];
#pragma unroll
    for (int i = 0; i < 8; ++i) {
        int idx = tid + 256 * i;     // 2048 = 16b * 128o
        As[(idx >> 7) * 132 + (idx & 127)] = A[idx];
    }
    __syncthreads();

    // ---- np via MFMA: wave w owns rows [m0+w*16, +16) ----
    const int row = m0 + w * 16 + c;
    const bool valid = row < M;
    const float* arow = in + (size_t)row * 128;

    f32x4 acc[8];
#pragma unroll
    for (int ot = 0; ot < 8; ++ot) acc[ot] = (f32x4){0.f, 0.f, 0.f, 0.f};

#pragma unroll
    for (int kb = 0; kb < 4; ++kb) {
        const int off = kb * 32 + q * 8;
        float4 f0 = make_float4(0.f, 0.f, 0.f, 0.f), f1 = f0;
        if (valid) {
            f0 = *(const float4*)(arow + off);
            f1 = *(const float4*)(arow + off + 4);
        }
        bf16x8 av;
        av[0] = f2bs(f0.x); av[1] = f2bs(f0.y); av[2] = f2bs(f0.z); av[3] = f2bs(f0.w);
        av[4] = f2bs(f1.x); av[5] = f2bs(f1.y); av[6] = f2bs(f1.z); av[7] = f2bs(f1.w);
#pragma unroll
        for (int ot = 0; ot < 8; ++ot) {
            bf16x8 bv = *(const bf16x8*)(w1b + (ot * 16 + c) * 128 + off);
            acc[ot] = __builtin_amdgcn_mfma_f32_16x16x32_bf16(av, bv, acc[ot], 0, 0, 0);
        }
    }
    // acc[ot][r] = np[m0 + w*16 + q*4 + r][ot*16 + c]

    // ---- scores ----
    float w2v[8];
#pragma unroll
    for (int ot = 0; ot < 8; ++ot) w2v[ot] = w2s[ot * 16 + c];

#pragma unroll
    for (int b = 0; b < 16; ++b) {
        float sp[4] = {0.f, 0.f, 0.f, 0.f};
#pragma unroll
        for (int ot = 0; ot < 8; ++ot) {
            float av = As[b * 132 + ot * 16 + c];
            float wv = w2v[ot];
#pragma unroll
            for (int r = 0; r < 4; ++r)
                sp[r] += fmaxf(acc[ot][r] + av, 0.f) * wv;
        }
#pragma unroll
        for (int off2 = 1; off2 < 16; off2 <<= 1)
#pragma unroll
            for (int r = 0; r < 4; ++r) sp[r] += __shfl_xor(sp[r], off2, 64);
        if (c == b) {
#pragma unroll
            for (int r = 0; r < 4; ++r)
                sl[b * 68 + w * 16 + q * 4 + r] = sp[r];
        }
    }
    __syncthreads();

    // ---- local softmax: wave w handles b in {w, w+4, w+8, w+12}, ml = lane ----
    const int lim = (M - m0 < 64) ? (M - m0) : 64;
#pragma unroll
    for (int i = 0; i < 4; ++i) {
        int b = w + 4 * i;
        float v = (lane < lim) ? sl[b * 68 + lane] : -INFINITY;
        float mx = v;
#pragma unroll
        for (int off2 = 1; off2 < 64; off2 <<= 1)
            mx = fmaxf(mx, __shfl_xor(mx, off2, 64));
        float p = (lane < lim) ? __expf(v - mx) : 0.f;
        ps[lane * 20 + b] = p;
        float s = p;
#pragma unroll
        for (int off2 = 1; off2 < 64; off2 <<= 1) s += __shfl_xor(s, off2, 64);
        if (lane == 0) {
            lmax_g[bid * 16 + b] = mx;
            lsum_g[bid * 16 + b] = s;
        }
    }
    __syncthreads();

    // ---- pool: thread (dd, bg) accumulates 8 b's ----
    const int dd = tid & 127, bg = tid >> 7;
    float pa[8];
#pragma unroll
    for (int j = 0; j < 8; ++j) pa[j] = 0.f;
#pragma unroll 4
    for (int ml = 0; ml < lim; ++ml) {
        float iv = in[(size_t)(m0 + ml) * 128 + dd];   // L1/L2 hot (phase-1 read)
        float4 p0 = *(float4*)&ps[ml * 20 + bg * 8];
        float4 p1 = *(float4*)&ps[ml * 20 + bg * 8 + 4];
        pa[0] += p0.x * iv; pa[1] += p0.y * iv;
        pa[2] += p0.z * iv; pa[3] += p0.w * iv;
        pa[4] += p1.x * iv; pa[5] += p1.y * iv;
        pa[6] += p1.z * iv; pa[7] += p1.w * iv;
    }
#pragma unroll
    for (int j = 0; j < 8; ++j)
        pacc[((size_t)bid * 16 + bg * 8 + j) * 128 + dd] = (ushort)f2bs(pa[j]);
}

__global__ __launch_bounds__(256) void kC1(
    const float* __restrict__ lmax_g, const float* __restrict__ lsum_g,
    const ushort* __restrict__ pacc, float* __restrict__ pacc2,
    float* __restrict__ lsum2, int nb) {
    const int b = blockIdx.x >> 4, s = blockIdx.x & 15;
    const int t = threadIdx.x;
    __shared__ float red[4];
    __shared__ float reda[2 * 128];
    __shared__ float redl[2];
    // gmax[b] (redundant per block; lmax is tiny and L2-hot)
    float mx = -INFINITY;
    for (int i = t; i < nb; i += 256) mx = fmaxf(mx, lmax_g[i * 16 + b]);
#pragma unroll
    for (int off = 1; off < 64; off <<= 1) mx = fmaxf(mx, __shfl_xor(mx, off, 64));
    if ((t & 63) == 0) red[t >> 6] = mx;
    __syncthreads();
    const float gmax = fmaxf(fmaxf(red[0], red[1]), fmaxf(red[2], red[3]));

    const int cs = (nb + 15) >> 4;
    const int blk0 = s * cs;
    int blk1 = blk0 + cs; if (blk1 > nb) blk1 = nb;
    const int dd = t & 127, h = t >> 7;
    float ac = 0.f, ls = 0.f;
    for (int blk = blk0 + h; blk < blk1; blk += 2) {
        float f = __expf(lmax_g[blk * 16 + b] - gmax);
        ac += f * bs2f(pacc[((size_t)blk * 16 + b) * 128 + dd]);
        ls += f * lsum_g[blk * 16 + b];
    }
    reda[h * 128 + dd] = ac;
    if (dd == 0) redl[h] = ls;
    __syncthreads();
    if (h == 0) {
        pacc2[((size_t)s * 16 + b) * 128 + dd] = reda[dd] + reda[128 + dd];
        if (dd == 0) lsum2[s * 16 + b] = redl[0] + redl[1];
    }
}

__global__ void kC2(const float* __restrict__ pacc2, const float* __restrict__ lsum2,
                    float* __restrict__ out) {
    const int b = blockIdx.x, t = threadIdx.x;   // 16 blocks x 128 threads
    float ac = 0.f, ls = 0.f;
#pragma unroll
    for (int s = 0; s < 16; ++s) {
        ac += pacc2[((size_t)s * 16 + b) * 128 + t];
        ls += lsum2[s * 16 + b];
    }
    out[b * 128 + t] = ac / ls;
}

extern "C" void kernel_launch(void* const* d_in, const int* in_sizes, int n_in,
                              void* d_out, int out_size, void* d_ws, size_t ws_size,
                              hipStream_t stream) {
    const float* xx = (const float*)d_in[0];
    const float* in = (const float*)d_in[1];
    // d_in[2] = adj, unused
    const float* W1 = (const float*)d_in[3];
    const float* W2 = (const float*)d_in[4];
    float* out = (float*)d_out;

    const int M = in_sizes[1] / 128;
    const int nb = (M + 63) / 64;

    float* ws = (float*)d_ws;
    float* A      = ws;                             // 2048
    float* lmax_g = A + 2048;                       // nb*16
    float* lsum_g = lmax_g + (size_t)nb * 16;       // nb*16
    float* pacc2  = lsum_g + (size_t)nb * 16;       // 256*128
    float* lsum2  = pacc2 + 256 * 128;              // 256
    ushort* w1b   = (ushort*)(lsum2 + 256);         // 16384
    ushort* pacc  = w1b + 16384;                    // nb*16*128  (~6.4 MB)
    // total ~6.8 MB of d_ws

    kA <<<72, 256, 0, stream>>>(W1, xx, w1b, A);
    kB <<<nb, 256, 0, stream>>>(in, w1b, W2, A, lmax_g, lsum_g, pacc, M);
    kC1<<<256, 256, 0, stream>>>(lmax_g, lsum_g, pacc, pacc2, lsum2, nb);
    kC2<<<16, 128, 0, stream>>>(pacc2, lsum2, out);
}

// Round 4
// 161.198 us; speedup vs baseline: 2.3520x; 1.0878x over previous
//
#include <hip/hip_runtime.h>
#include <hip/hip_bf16.h>
#include <math.h>

// B=16, D=128, OUT=128, M runtime (100000).
// kA : blocks 0-63: w1b = bf16(W1 node half); blocks 64-71: A[b][o] anchor GEMM
// kB : fused per-64-row block, input tile staged ONCE into LDS as bf16:
//        - np via bf16 MFMA (A-frags = ds_read_b128 from LDS tile, B-frags = w1b L2-hot)
//        - scores s[b][m] = sum_o relu(np+A[b][o])*w2[o]  (shuffle-reduced)
//        - block-local softmax (lmax/lsum) ; pool partials from the SAME LDS tile
//      writes lmax, lsum (fp32), pacc (bf16)
// kC1: 16 b x 16 splits: global-max rescale + partial reduction over blocks
// kC2: final 16-way reduce -> out

typedef __attribute__((ext_vector_type(8))) short bf16x8;
typedef __attribute__((ext_vector_type(4))) float f32x4;

__device__ __forceinline__ short f2bs(float f) {
    __hip_bfloat16 h = __float2bfloat16(f);
    return *reinterpret_cast<short*>(&h);
}
__device__ __forceinline__ float bs2f(ushort u) {
    union { unsigned int i; float f; } v; v.i = ((unsigned)u) << 16; return v.f;
}

__global__ __launch_bounds__(256) void kA(const float* __restrict__ W1,
                                          const float* __restrict__ xx,
                                          ushort* __restrict__ w1b,
                                          float* __restrict__ A) {
    const int bi = blockIdx.x, t = threadIdx.x;
    if (bi < 64) {
        int idx = bi * 256 + t;              // 16384 = 128o * 128d
        int o = idx >> 7, d = idx & 127;
        w1b[idx] = (ushort)f2bs(W1[o * 256 + 128 + d]);
        return;
    }
    __shared__ float xxs[16 * 132];
    __shared__ float w1s[16 * 132];
    const int og0 = (bi - 64) * 16;
#pragma unroll
    for (int i = 0; i < 2; ++i) {
        int idx = t + 256 * i;               // 512 float4 = 16 rows * 32
        int r = idx >> 5, c4 = (idx & 31) << 2;
        *(float4*)&xxs[r * 132 + c4] = *(const float4*)&xx[r * 128 + c4];
        *(float4*)&w1s[r * 132 + c4] = *(const float4*)&W1[(og0 + r) * 256 + c4];
    }
    __syncthreads();
    const int ol = t >> 4, b = t & 15;
    float acc = 0.f;
#pragma unroll
    for (int d4 = 0; d4 < 32; ++d4) {
        float4 xv = *(float4*)&xxs[b * 132 + d4 * 4];
        float4 wv = *(float4*)&w1s[ol * 132 + d4 * 4];
        acc += xv.x * wv.x + xv.y * wv.y + xv.z * wv.z + xv.w * wv.w;
    }
    A[b * 128 + og0 + ol] = acc;
}

__global__ __launch_bounds__(256, 4) void kB(
    const float* __restrict__ in, const ushort* __restrict__ w1b,
    const float* __restrict__ W2, const float* __restrict__ A,
    float* __restrict__ lmax_g, float* __restrict__ lsum_g,
    ushort* __restrict__ pacc, int M) {
    __shared__ ushort ins[64 * 136];  // bf16 in-tile [m][d], row stride 136 (bank skew)
    __shared__ float As[16 * 128];    // A[b][o]
    __shared__ float w2s[128];
    __shared__ float sl[16 * 64];     // scores [b][ml]
    __shared__ float ps[64 * 20];     // p      [ml][b]

    const int tid = threadIdx.x, bid = blockIdx.x;
    const int m0 = bid * 64;
    const int w = tid >> 6, lane = tid & 63;
    const int c = lane & 15, q = lane >> 4;
    const int lim = (M - m0 < 64) ? (M - m0) : 64;

    // ---- stage input tile -> LDS as bf16 (coalesced float4 global reads) ----
#pragma unroll
    for (int i = 0; i < 8; ++i) {
        int idx = tid + 256 * i;              // 2048 float4s = 64 rows * 32
        int r = idx >> 5, c4 = (idx & 31) << 2;
        float4 v = make_float4(0.f, 0.f, 0.f, 0.f);
        if (r < lim) v = *(const float4*)&in[(size_t)(m0 + r) * 128 + c4];
        ushort4 u;
        u.x = (ushort)f2bs(v.x); u.y = (ushort)f2bs(v.y);
        u.z = (ushort)f2bs(v.z); u.w = (ushort)f2bs(v.w);
        *(ushort4*)&ins[r * 136 + c4] = u;    // ds_write_b64
    }
    if (tid < 128) w2s[tid] = W2[tid];
#pragma unroll
    for (int i = 0; i < 8; ++i) {
        int idx = tid + 256 * i;              // 2048 = 16b * 128o
        As[idx] = A[idx];
    }
    __syncthreads();

    // ---- np via MFMA: wave w owns rows [m0+w*16, +16) ----
    const ushort* arow = &ins[(w * 16 + c) * 136];
    f32x4 acc[8];
#pragma unroll
    for (int ot = 0; ot < 8; ++ot) acc[ot] = (f32x4){0.f, 0.f, 0.f, 0.f};

#pragma unroll
    for (int kb = 0; kb < 4; ++kb) {
        bf16x8 av = *(const bf16x8*)(arow + kb * 32 + q * 8);   // ds_read_b128
#pragma unroll
        for (int ot = 0; ot < 8; ++ot) {
            bf16x8 bv = *(const bf16x8*)(w1b + (ot * 16 + c) * 128 + kb * 32 + q * 8);
            acc[ot] = __builtin_amdgcn_mfma_f32_16x16x32_bf16(av, bv, acc[ot], 0, 0, 0);
        }
    }
    // acc[ot][r] = np[m0 + w*16 + q*4 + r][ot*16 + c]

    // ---- scores ----
    float w2v[8];
#pragma unroll
    for (int ot = 0; ot < 8; ++ot) w2v[ot] = w2s[ot * 16 + c];

#pragma unroll
    for (int b = 0; b < 16; ++b) {
        float sp[4] = {0.f, 0.f, 0.f, 0.f};
#pragma unroll
        for (int ot = 0; ot < 8; ++ot) {
            float av = As[b * 128 + ot * 16 + c];
            float wv = w2v[ot];
#pragma unroll
            for (int r = 0; r < 4; ++r)
                sp[r] += fmaxf(acc[ot][r] + av, 0.f) * wv;
        }
#pragma unroll
        for (int off2 = 1; off2 < 16; off2 <<= 1)
#pragma unroll
            for (int r = 0; r < 4; ++r) sp[r] += __shfl_xor(sp[r], off2, 64);
        if (c == b) {
#pragma unroll
            for (int r = 0; r < 4; ++r)
                sl[b * 64 + w * 16 + q * 4 + r] = sp[r];
        }
    }
    __syncthreads();

    // ---- local softmax: wave w handles b in {w, w+4, w+8, w+12}, ml = lane ----
#pragma unroll
    for (int i = 0; i < 4; ++i) {
        int b = w + 4 * i;
        float v = (lane < lim) ? sl[b * 64 + lane] : -INFINITY;
        float mx = v;
#pragma unroll
        for (int off2 = 1; off2 < 64; off2 <<= 1)
            mx = fmaxf(mx, __shfl_xor(mx, off2, 64));
        float p = (lane < lim) ? __expf(v - mx) : 0.f;
        ps[lane * 20 + b] = p;
        float s = p;
#pragma unroll
        for (int off2 = 1; off2 < 64; off2 <<= 1) s += __shfl_xor(s, off2, 64);
        if (lane == 0) {
            lmax_g[bid * 16 + b] = mx;
            lsum_g[bid * 16 + b] = s;
        }
    }
    __syncthreads();

    // ---- pool from the SAME LDS tile: thread (dd, bg) accumulates 8 b's ----
    const int dd = tid & 127, bg = tid >> 7;
    float pa[8];
#pragma unroll
    for (int j = 0; j < 8; ++j) pa[j] = 0.f;
#pragma unroll 4
    for (int ml = 0; ml < lim; ++ml) {
        float iv = bs2f(ins[ml * 136 + dd]);            // ds_read_u16, conflict-free
        float4 p0 = *(float4*)&ps[ml * 20 + bg * 8];    // broadcast
        float4 p1 = *(float4*)&ps[ml * 20 + bg * 8 + 4];
        pa[0] += p0.x * iv; pa[1] += p0.y * iv;
        pa[2] += p0.z * iv; pa[3] += p0.w * iv;
        pa[4] += p1.x * iv; pa[5] += p1.y * iv;
        pa[6] += p1.z * iv; pa[7] += p1.w * iv;
    }
#pragma unroll
    for (int j = 0; j < 8; ++j)
        pacc[((size_t)bid * 16 + bg * 8 + j) * 128 + dd] = (ushort)f2bs(pa[j]);
}

__global__ __launch_bounds__(256) void kC1(
    const float* __restrict__ lmax_g, const float* __restrict__ lsum_g,
    const ushort* __restrict__ pacc, float* __restrict__ pacc2,
    float* __restrict__ lsum2, int nb) {
    const int b = blockIdx.x >> 4, s = blockIdx.x & 15;
    const int t = threadIdx.x;
    __shared__ float red[4];
    __shared__ float reda[2 * 128];
    __shared__ float redl[2];
    float mx = -INFINITY;
    for (int i = t; i < nb; i += 256) mx = fmaxf(mx, lmax_g[i * 16 + b]);
#pragma unroll
    for (int off = 1; off < 64; off <<= 1) mx = fmaxf(mx, __shfl_xor(mx, off, 64));
    if ((t & 63) == 0) red[t >> 6] = mx;
    __syncthreads();
    const float gmax = fmaxf(fmaxf(red[0], red[1]), fmaxf(red[2], red[3]));

    const int cs = (nb + 15) >> 4;
    const int blk0 = s * cs;
    int blk1 = blk0 + cs; if (blk1 > nb) blk1 = nb;
    const int dd = t & 127, h = t >> 7;
    float ac = 0.f, ls = 0.f;
    for (int blk = blk0 + h; blk < blk1; blk += 2) {
        float f = __expf(lmax_g[blk * 16 + b] - gmax);
        ac += f * bs2f(pacc[((size_t)blk * 16 + b) * 128 + dd]);
        ls += f * lsum_g[blk * 16 + b];
    }
    reda[h * 128 + dd] = ac;
    if (dd == 0) redl[h] = ls;
    __syncthreads();
    if (h == 0) {
        pacc2[((size_t)s * 16 + b) * 128 + dd] = reda[dd] + reda[128 + dd];
        if (dd == 0) lsum2[s * 16 + b] = redl[0] + redl[1];
    }
}

__global__ void kC2(const float* __restrict__ pacc2, const float* __restrict__ lsum2,
                    float* __restrict__ out) {
    const int b = blockIdx.x, t = threadIdx.x;   // 16 blocks x 128 threads
    float ac = 0.f, ls = 0.f;
#pragma unroll
    for (int s = 0; s < 16; ++s) {
        ac += pacc2[((size_t)s * 16 + b) * 128 + t];
        ls += lsum2[s * 16 + b];
    }
    out[b * 128 + t] = ac / ls;
}

extern "C" void kernel_launch(void* const* d_in, const int* in_sizes, int n_in,
                              void* d_out, int out_size, void* d_ws, size_t ws_size,
                              hipStream_t stream) {
    const float* xx = (const float*)d_in[0];
    const float* in = (const float*)d_in[1];
    // d_in[2] = adj, unused
    const float* W1 = (const float*)d_in[3];
    const float* W2 = (const float*)d_in[4];
    float* out = (float*)d_out;

    const int M = in_sizes[1] / 128;
    const int nb = (M + 63) / 64;

    float* ws = (float*)d_ws;
    float* A      = ws;                             // 2048
    float* lmax_g = A + 2048;                       // nb*16
    float* lsum_g = lmax_g + (size_t)nb * 16;       // nb*16
    float* pacc2  = lsum_g + (size_t)nb * 16;       // 256*128
    float* lsum2  = pacc2 + 256 * 128;              // 256
    ushort* w1b   = (ushort*)(lsum2 + 256);         // 16384
    ushort* pacc  = w1b + 16384;                    // nb*16*128  (~6.4 MB)
    // total ~6.8 MB of d_ws

    kA <<<72, 256, 0, stream>>>(W1, xx, w1b, A);
    kB <<<nb, 256, 0, stream>>>(in, w1b, W2, A, lmax_g, lsum_g, pacc, M);
    kC1<<<256, 256, 0, stream>>>(lmax_g, lsum_g, pacc, pacc2, lsum2, nb);
    kC2<<<16, 128, 0, stream>>>(pacc2, lsum2, out);
}